// Round 17
// baseline (531.123 us; speedup 1.0000x reference)
//
#include <hip/hip_runtime.h>

#define NPTS 40000
#define NEDGE 1000000
#define BN_EPS 1e-5f

typedef short bf16x8 __attribute__((ext_vector_type(8)));
typedef float f32x4 __attribute__((ext_vector_type(4)));

__device__ __forceinline__ unsigned short f2bf(float x) {
    unsigned u = __float_as_uint(x);
    return (unsigned short)((u + 0x7FFFu + ((u >> 16) & 1u)) >> 16);  // RTN-even
}

// ===========================================================================
// Edge geometry: validity + cell + factorized weights.
// ===========================================================================
__device__ inline bool edge_geom(const float* rel_pos, const int* ws_ptr, int e,
                                 int& cell, float4& w4) {
    float ws = (float)ws_ptr[0];
    float inv_ws = 1.0f / ws;
    float ux = rel_pos[2 * e] * inv_ws;
    float uy = rel_pos[2 * e + 1] * inv_ws;
    float q = 1.0f - (ux * ux + uy * uy);
    if (!(q > 0.0f)) return false;
    float win = q * q * q;
    float gx = fminf(fmaxf((ux + 1.0f) * 1.5f, 0.0f), 3.0f);
    float gy = fminf(fmaxf((uy + 1.0f) * 1.5f, 0.0f), 3.0f);
    int ix = (int)floorf(gx); ix = ix < 0 ? 0 : (ix > 2 ? 2 : ix);
    int iy = (int)floorf(gy); iy = iy < 0 ? 0 : (iy > 2 ? 2 : iy);
    float fx = gx - (float)ix;
    float fy = gy - (float)iy;
    cell = ix * 4 + iy;
    w4 = make_float4((1.f - fx) * win, fx * win, fy, 0.f);
    return true;
}

__global__ void hist_kernel(const float* __restrict__ rel_pos,
                            const int* __restrict__ receivers,
                            const int* __restrict__ ws_ptr,
                            int* __restrict__ cnt) {
    int e = blockIdx.x * blockDim.x + threadIdx.x;
    if (e >= NEDGE) return;
    int cell; float4 w4;
    if (edge_geom(rel_pos, ws_ptr, e, cell, w4))
        atomicAdd(&cnt[receivers[e]], 1);
}

// one block, 1024 threads: exclusive scan of 40000 counts -> rowptr[40001]
__global__ __launch_bounds__(1024) void scan_kernel(const int* __restrict__ cnt,
                                                    int* __restrict__ rowptr) {
    __shared__ int part[1024];
    int t = threadIdx.x;
    const int CHUNK = 40;  // 1000 threads * 40 = 40000
    int base = t * CHUNK;
    int s = 0;
    if (t < 1000)
        for (int i = 0; i < CHUNK; ++i) s += cnt[base + i];
    part[t] = s;
    __syncthreads();
    for (int off = 1; off < 1024; off <<= 1) {
        int v = (t >= off) ? part[t - off] : 0;
        __syncthreads();
        part[t] += v;
        __syncthreads();
    }
    int excl = (t == 0) ? 0 : part[t - 1];
    if (t < 1000) {
        int run = excl;
        for (int i = 0; i < CHUNK; ++i) { rowptr[base + i] = run; run += cnt[base + i]; }
        if (t == 999) rowptr[NPTS] = run;
    }
}

__global__ void fill_kernel(const float* __restrict__ rel_pos,
                            const int* __restrict__ receivers,
                            const int* __restrict__ senders,
                            const int* __restrict__ ws_ptr,
                            const int* __restrict__ rowptr,
                            int* __restrict__ cursor,
                            int2* __restrict__ sc,
                            float4* __restrict__ ew4) {
    int e = blockIdx.x * blockDim.x + threadIdx.x;
    if (e >= NEDGE) return;
    int cell; float4 w4;
    if (!edge_geom(rel_pos, ws_ptr, e, cell, w4)) return;
    int recv = receivers[e];
    int pos = rowptr[recv] + atomicAdd(&cursor[recv], 1);
    sc[pos] = make_int2(senders[e], cell);
    ew4[pos] = w4;
}

// ===========================================================================
// Merged W repack (all 4 weights, one launch) into bf16 MFMA B-fragment
// layout: Wp[((cb*nKS+ks)*64+l)*8+j] = bf16(W[ks*32+(l>>4)*8+j][cb*16+(l&15)])
// ===========================================================================
__global__ void pack_all_kernel(const float* __restrict__ W1, const float* __restrict__ W2,
                                const float* __restrict__ W3, const float* __restrict__ W4,
                                unsigned short* __restrict__ Wp1, unsigned short* __restrict__ Wp2,
                                unsigned short* __restrict__ Wp3, unsigned short* __restrict__ Wp4) {
    int idx = blockIdx.x * 256 + threadIdx.x;
    const float* W; unsigned short* Wp; int M, COUT, base;
    if (idx < 65536)       { W = W1; Wp = Wp1; M = 1024; COUT = 64; base = 0; }
    else if (idx < 98304)  { W = W2; Wp = Wp2; M = 1024; COUT = 32; base = 65536; }
    else if (idx < 131072) { W = W3; Wp = Wp3; M = 512;  COUT = 64; base = 98304; }
    else if (idx < 163840) { W = W4; Wp = Wp4; M = 1024; COUT = 32; base = 131072; }
    else return;
    int i = idx - base;
    int nKS = M / 32;
    int j = i & 7, l = (i >> 3) & 63, t = i >> 9;
    int ks = t % nKS, cb = t / nKS;
    int m = ks * 32 + (l >> 4) * 8 + j;
    int col = cb * 16 + (l & 15);
    Wp[i] = f2bf(W[(size_t)m * COUT + col]);
}

// ===========================================================================
// Per-edge register accumulation.
// ===========================================================================
template <int VEC>
__device__ __forceinline__ void do_edge(bool act, int e,
                                        const int2* __restrict__ sc,
                                        const float4* __restrict__ ew4,
                                        const float* __restrict__ fbase,
                                        int fstride, float acc[16][VEC]) {
    int2 rec = sc[e];
    float4 w = ew4[e];
    int sender = act ? rec.x : 0;
    float wx0 = act ? w.x : 0.f;
    float wx1 = act ? w.y : 0.f;
    float fy = w.z;
    int ix = rec.y >> 2, iy = rec.y & 3;
    float wy0 = 1.f - fy, wy1 = fy;
    float wxv[4], wyv[4];
#pragma unroll
    for (int c = 0; c < 4; ++c) {
        wxv[c] = (c == ix) ? wx0 : ((c == ix + 1) ? wx1 : 0.f);
        wyv[c] = (c == iy) ? wy0 : ((c == iy + 1) ? wy1 : 0.f);
    }
    float f[VEC];
    const float* fp = fbase + (size_t)sender * fstride;
    if constexpr (VEC == 4) {
        float4 v = *(const float4*)fp;
        f[0] = v.x; f[1] = v.y; f[2] = v.z; f[3] = v.w;
    } else {
        float2 v = *(const float2*)fp;
        f[0] = v.x; f[1] = v.y;
    }
#pragma unroll
    for (int cx = 0; cx < 4; ++cx) {
        float wxc = wxv[cx];
#pragma unroll
        for (int cy = 0; cy < 4; ++cy) {
            float wc = wxc * wyv[cy];
#pragma unroll
            for (int j = 0; j < VEC; ++j)
                acc[cx * 4 + cy][j] = fmaf(wc, f[j], acc[cx * 4 + cy][j]);
        }
    }
}

// ===========================================================================
// Fused cconv layer (MFMA phase 2) + fused BN partial stats.
// MODE 0: feat plain [N][CIN].  MODE 1: concat(x,y) gather (layer 1).
// Epilogue: per-block column sum/sumsq via shfl_xor -> part[block][2*COUT]
// (deterministic two-stage BN; removes 4 stats kernels + P re-reads).
// ===========================================================================
template <int CIN, int COUT, int MODE>
__global__ __launch_bounds__(256, 4) void fused_layer(const float* __restrict__ feat,
                                                      const float* __restrict__ xin,
                                                      const float* __restrict__ yin,
                                                      const int2* __restrict__ sc,
                                                      const float4* __restrict__ ew4,
                                                      const int* __restrict__ rowptr,
                                                      const unsigned short* __restrict__ Wp,
                                                      const float* __restrict__ a,
                                                      float* __restrict__ P,
                                                      float* __restrict__ part) {
    constexpr int RB = 16;            // receivers per block
    constexpr int M = 16 * CIN;       // GEMM K dimension
    constexpr int LDB = M + 8;        // bf16 row stride (pad 8)
    constexpr int nKS = M / 32;       // MFMA K-steps
    constexpr int VEC = CIN / 16;
    constexpr int CT = COUT / 16;     // colblocks (4 or 2)
    __shared__ short S_bf[RB * LDB];
    __shared__ float Rred[CT == 2 ? 512 : 4];

    int tid = threadIdx.x;
    int lane = tid & 63;
    int wave = tid >> 6;
    int slot = lane >> 4;
    int q = lane & 15;
    int rloc = wave * 4 + slot;
    int rglob = blockIdx.x * RB + rloc;
    int rs = rowptr[rglob];
    int deg = rowptr[rglob + 1] - rs;
    int md = deg;
    md = max(md, __shfl_xor(md, 16));
    md = max(md, __shfl_xor(md, 32));

    // feat base: MODE 1 selects x/y half statically per lane (q<8 -> x)
    const float* fbase;
    int fstride;
    if constexpr (MODE == 1) {
        fbase = (q < 8) ? (xin + q * VEC) : (yin + (q - 8) * VEC);
        fstride = 32;
    } else {
        fbase = feat + q * VEC;
        fstride = CIN;
    }

    float acc[16][VEC];
#pragma unroll
    for (int cc = 0; cc < 16; ++cc)
#pragma unroll
        for (int j = 0; j < VEC; ++j) acc[cc][j] = 0.f;

#pragma unroll 2
    for (int k = 0; k < md; ++k) {
        bool act = k < deg;
        do_edge<VEC>(act, rs + (act ? k : 0), sc, ew4, fbase, fstride, acc);
    }

    // --- handoff: acc -> bf16 LDS rows ---
    {
        short* srow = &S_bf[rloc * LDB + q * VEC];
#pragma unroll
        for (int cc = 0; cc < 16; ++cc) {
            if constexpr (VEC == 4) {
                unsigned lo = (unsigned)f2bf(acc[cc][0]) | ((unsigned)f2bf(acc[cc][1]) << 16);
                unsigned hi = (unsigned)f2bf(acc[cc][2]) | ((unsigned)f2bf(acc[cc][3]) << 16);
                *(uint2*)(srow + cc * CIN) = make_uint2(lo, hi);
            } else {
                unsigned lo = (unsigned)f2bf(acc[cc][0]) | ((unsigned)f2bf(acc[cc][1]) << 16);
                *(unsigned*)(srow + cc * CIN) = lo;
            }
        }
    }
    __syncthreads();

    // --- phase 2: MFMA GEMM ---
    int row16 = lane & 15;
    int kgrp = lane >> 4;
    f32x4 c = {0.f, 0.f, 0.f, 0.f};
    int cb, ks0;
    constexpr int KS_PER = (CT == 4) ? nKS : nKS / 2;
    if constexpr (CT == 4) { cb = wave; ks0 = 0; }
    else { cb = wave & 1; ks0 = (wave >> 1) * KS_PER; }

    const short* abase = &S_bf[row16 * LDB + kgrp * 8];
    const bf16x8* wfrag = (const bf16x8*)Wp;
    size_t wbase = (size_t)(cb * nKS + ks0) * 64 + lane;
#pragma unroll 8
    for (int kk = 0; kk < KS_PER; ++kk) {
        bf16x8 af = *(const bf16x8*)(abase + (size_t)(ks0 + kk) * 32);
        bf16x8 bf = wfrag[wbase + (size_t)kk * 64];
        c = __builtin_amdgcn_mfma_f32_16x16x32_bf16(af, bf, c, 0, 0, 0);
    }

    // --- write out + per-block BN partials ---
    if constexpr (CT == 2) {
        if (wave >= 2) {
#pragma unroll
            for (int i = 0; i < 4; ++i)
                Rred[cb * 256 + (kgrp * 4 + i) * 16 + row16] = c[i];
        }
        __syncthreads();
        if (wave < 2) {
            float sp = 0.f, sq = 0.f;
#pragma unroll
            for (int i = 0; i < 4; ++i) {
                int row = kgrp * 4 + i;
                int n = blockIdx.x * RB + row;
                float v = a[n] * (c[i] + Rred[cb * 256 + row * 16 + row16]);
                P[(size_t)n * COUT + cb * 16 + row16] = v;
                sp += v; sq += v * v;
            }
            sp += __shfl_xor(sp, 16); sp += __shfl_xor(sp, 32);
            sq += __shfl_xor(sq, 16); sq += __shfl_xor(sq, 32);
            if (kgrp == 0) {
                part[(size_t)blockIdx.x * 2 * COUT + cb * 16 + row16] = sp;
                part[(size_t)blockIdx.x * 2 * COUT + COUT + cb * 16 + row16] = sq;
            }
        }
    } else {
        float sp = 0.f, sq = 0.f;
#pragma unroll
        for (int i = 0; i < 4; ++i) {
            int row = kgrp * 4 + i;
            int n = blockIdx.x * RB + row;
            float v = a[n] * c[i];
            P[(size_t)n * COUT + cb * 16 + row16] = v;
            sp += v; sq += v * v;
        }
        sp += __shfl_xor(sp, 16); sp += __shfl_xor(sp, 32);
        sq += __shfl_xor(sq, 16); sq += __shfl_xor(sq, 32);
        if (kgrp == 0) {
            part[(size_t)blockIdx.x * 2 * COUT + cb * 16 + row16] = sp;
            part[(size_t)blockIdx.x * 2 * COUT + COUT + cb * 16 + row16] = sq;
        }
    }
}

// ===========================================================================
// BN finalize: reduce 2500 per-block partials -> scale/shift.
// ===========================================================================
template <int COUT>
__global__ __launch_bounds__(256) void finalize_bn_kernel(const float* __restrict__ part,
                                                          const float* __restrict__ g,
                                                          const float* __restrict__ b,
                                                          float* __restrict__ scb) {
    constexpr int C2 = 2 * COUT;
    constexpr int NG = 256 / C2;          // 2 (COUT=64) or 4 (COUT=32)
    constexpr int NB = NPTS / 16;         // 2500
    constexpr int PER = NB / NG;          // 1250 or 625
    __shared__ float ls[256];
    int tid = threadIdx.x;
    int d = tid % C2;
    int gi = tid / C2;
    float s = 0.f;
    int k0 = gi * PER;
    for (int k = k0; k < k0 + PER; ++k) s += part[(size_t)k * C2 + d];
    ls[tid] = s;
    __syncthreads();
    float tot = 0.f;
    if (tid < C2) {
        tot = ls[tid];
        for (int g2 = 1; g2 < NG; ++g2) tot += ls[tid + g2 * C2];
    }
    __syncthreads();
    if (tid < C2) ls[tid] = tot;
    __syncthreads();
    if (tid < COUT) {
        float sum = ls[tid], ssq = ls[COUT + tid];
        float mean = sum / (float)NPTS;
        float var = ssq / (float)NPTS - mean * mean;
        float inv = rsqrtf(var + BN_EPS);
        float scale = inv * g[tid];
        scb[tid] = scale;
        scb[COUT + tid] = b[tid] - mean * scale;
    }
}

template <int COUT>
__global__ void apply_relu_kernel(float* __restrict__ P, const float* __restrict__ scb) {
    int t = blockIdx.x * blockDim.x + threadIdx.x;
    if (t >= NPTS * COUT) return;
    int d = t % COUT;
    float v = P[t] * scb[d] + scb[COUT + d];
    P[t] = fmaxf(v, 0.0f);
}

__global__ void apply_sigmix_kernel(const float* __restrict__ P,
                                    const float* __restrict__ scb,
                                    const float* __restrict__ x,
                                    const float* __restrict__ y,
                                    float* __restrict__ out) {
    int t = blockIdx.x * blockDim.x + threadIdx.x;
    if (t >= NPTS * 32) return;
    int d = t & 31;
    float v = P[t] * scb[d] + scb[32 + d];
    float w = 1.0f / (1.0f + expf(-v));
    out[t] = 2.0f * x[t] * w + 2.0f * y[t] * (1.0f - w);
}

extern "C" void kernel_launch(void* const* d_in, const int* in_sizes, int n_in,
                              void* d_out, int out_size, void* d_ws, size_t ws_size,
                              hipStream_t stream) {
    const float* x = (const float*)d_in[0];
    const float* y = (const float*)d_in[1];
    const int* senders = (const int*)d_in[2];
    const int* receivers = (const int*)d_in[3];
    const float* rel_pos = (const float*)d_in[4];
    const int* ws_ptr = (const int*)d_in[5];
    const float* a = (const float*)d_in[6];
    const float* W1 = (const float*)d_in[7];
    const float* W2 = (const float*)d_in[8];
    const float* W3 = (const float*)d_in[9];
    const float* W4 = (const float*)d_in[10];
    const float* g1 = (const float*)d_in[11];
    const float* b1 = (const float*)d_in[12];
    const float* g2 = (const float*)d_in[13];
    const float* b2 = (const float*)d_in[14];
    const float* g3 = (const float*)d_in[15];
    const float* b3 = (const float*)d_in[16];
    const float* g4 = (const float*)d_in[17];
    const float* b4 = (const float*)d_in[18];

    char* ws = (char*)d_ws;
    size_t off = 0;
    auto alloc = [&](size_t bytes) -> void* {
        void* p = ws + off;
        off += (bytes + 255) & ~(size_t)255;
        return p;
    };
    int* cnt = (int*)alloc((size_t)NPTS * sizeof(int));      // contiguous with
    int* cursor = (int*)alloc((size_t)NPTS * sizeof(int));   // cursor: 1 memset
    int* rowptr = (int*)alloc((size_t)(NPTS + 1) * sizeof(int));
    int2* sc = (int2*)alloc((size_t)(NEDGE + 4) * sizeof(int2));
    float4* ew4 = (float4*)alloc((size_t)(NEDGE + 4) * sizeof(float4));
    float* xa = (float*)alloc((size_t)NPTS * 64 * sizeof(float));  // P3
    float* P1 = (float*)alloc((size_t)NPTS * 64 * sizeof(float));
    float* P2 = (float*)alloc((size_t)NPTS * 32 * sizeof(float));  // also P4
    float* xo = (float*)alloc((size_t)NPTS * 32 * sizeof(float));
    float* part = (float*)alloc((size_t)(NPTS / 16) * 128 * sizeof(float));
    float* scb = (float*)alloc(2 * 64 * sizeof(float));
    unsigned short* Wp1 = (unsigned short*)alloc((size_t)1024 * 64 * 2);
    unsigned short* Wp2 = (unsigned short*)alloc((size_t)1024 * 32 * 2);
    unsigned short* Wp3 = (unsigned short*)alloc((size_t)512 * 64 * 2);
    unsigned short* Wp4 = (unsigned short*)alloc((size_t)1024 * 32 * 2);
    (void)ws_size; (void)in_sizes; (void)n_in; (void)out_size;

    // --- prologue: packs (1 launch), CSR build, single memset ---
    pack_all_kernel<<<640, 256, 0, stream>>>(W1, W2, W3, W4, Wp1, Wp2, Wp3, Wp4);
    hipMemsetAsync(cnt, 0, (size_t)2 * NPTS * sizeof(int), stream);  // cnt+cursor
    hist_kernel<<<(NEDGE + 255) / 256, 256, 0, stream>>>(rel_pos, receivers, ws_ptr, cnt);
    scan_kernel<<<1, 1024, 0, stream>>>(cnt, rowptr);
    fill_kernel<<<(NEDGE + 255) / 256, 256, 0, stream>>>(rel_pos, receivers, senders, ws_ptr,
                                                         rowptr, cursor, sc, ew4);

    // Layer 1: cconv(concat(x,y); W1) -> P1 (+stats), relu(bn) in place
    fused_layer<64, 64, 1><<<NPTS / 16, 256, 0, stream>>>(nullptr, x, y, sc, ew4, rowptr,
                                                          Wp1, a, P1, part);
    finalize_bn_kernel<64><<<1, 256, 0, stream>>>(part, g1, b1, scb);
    apply_relu_kernel<64><<<(NPTS * 64 + 255) / 256, 256, 0, stream>>>(P1, scb);

    // Layer 2: cconv(P1; W2) -> P2 (+stats), sigmoid-mix -> xo
    fused_layer<64, 32, 0><<<NPTS / 16, 256, 0, stream>>>(P1, nullptr, nullptr, sc, ew4, rowptr,
                                                          Wp2, a, P2, part);
    finalize_bn_kernel<32><<<1, 256, 0, stream>>>(part, g2, b2, scb);
    apply_sigmix_kernel<<<(NPTS * 32 + 255) / 256, 256, 0, stream>>>(P2, scb, x, y, xo);

    // Layer 3: cconv(xo; W3) -> xa (+stats), relu(bn) in place
    fused_layer<32, 64, 0><<<NPTS / 16, 256, 0, stream>>>(xo, nullptr, nullptr, sc, ew4, rowptr,
                                                          Wp3, a, xa, part);
    finalize_bn_kernel<64><<<1, 256, 0, stream>>>(part, g3, b3, scb);
    apply_relu_kernel<64><<<(NPTS * 64 + 255) / 256, 256, 0, stream>>>(xa, scb);

    // Layer 4: cconv(xa; W4) -> P2 (+stats), sigmoid-mix -> out
    fused_layer<64, 32, 0><<<NPTS / 16, 256, 0, stream>>>(xa, nullptr, nullptr, sc, ew4, rowptr,
                                                          Wp4, a, P2, part);
    finalize_bn_kernel<32><<<1, 256, 0, stream>>>(part, g4, b4, scb);
    apply_sigmix_kernel<<<(NPTS * 32 + 255) / 256, 256, 0, stream>>>(P2, scb, x, y, (float*)d_out);
}